// Round 1
// baseline (2080.503 us; speedup 1.0000x reference)
//
#include <hip/hip_runtime.h>

#define BN 256   // B*N
#define D  2048
#define C  256
#define E  128
#define M  4096
#define V  10

// ---------------------------------------------------------------------------
// K1: xp[c][bn][e] = sum_d emb[bn][d] * proj[c][d][e]
// grid (2 bn-tiles, 256 c), 256 threads, tile 128x128, K chunks of 32,
// thread tile 8x8.
// ---------------------------------------------------------------------------
__global__ __launch_bounds__(256) void k1_xp(const float* __restrict__ emb,
                                             const float* __restrict__ proj,
                                             float* __restrict__ xp) {
  const int c   = blockIdx.y;
  const int bn0 = blockIdx.x * 128;
  const int tid = threadIdx.x;
  const int ty  = tid >> 4;   // 0..15 row group
  const int tx  = tid & 15;   // 0..15 col group

  __shared__ __align__(16) float As[32][128];  // [k][row]  (transposed)
  __shared__ __align__(16) float Bs[32][128];  // [k][e]

  float acc[8][8];
#pragma unroll
  for (int i = 0; i < 8; ++i)
#pragma unroll
    for (int j = 0; j < 8; ++j) acc[i][j] = 0.0f;

  const int srow = tid >> 1;          // 0..127 (A stage row)
  const int skof = (tid & 1) * 16;    // 0/16   (A stage k offset)
  const int brow = tid >> 3;          // 0..31  (B stage k row)
  const int beof = (tid & 7) * 16;    // B stage e offset

  const float* embp  = emb + (size_t)(bn0 + srow) * D + skof;
  const float* projp = proj + (size_t)c * D * E + (size_t)brow * E + beof;

  for (int k0 = 0; k0 < D; k0 += 32) {
    __syncthreads();
    // stage A transposed: As[k][row]
#pragma unroll
    for (int q = 0; q < 4; ++q) {
      float4 va = *(const float4*)(embp + k0 + q * 4);
      As[skof + q * 4 + 0][srow] = va.x;
      As[skof + q * 4 + 1][srow] = va.y;
      As[skof + q * 4 + 2][srow] = va.z;
      As[skof + q * 4 + 3][srow] = va.w;
    }
    // stage B direct: Bs[k][e]
#pragma unroll
    for (int q = 0; q < 4; ++q) {
      *(float4*)&Bs[brow][beof + q * 4] =
          *(const float4*)(projp + (size_t)k0 * E + q * 4);
    }
    __syncthreads();
#pragma unroll
    for (int k = 0; k < 32; ++k) {
      float a[8], b[8];
      *(float4*)&a[0] = *(const float4*)&As[k][ty * 8];
      *(float4*)&a[4] = *(const float4*)&As[k][ty * 8 + 4];
      *(float4*)&b[0] = *(const float4*)&Bs[k][tx * 8];
      *(float4*)&b[4] = *(const float4*)&Bs[k][tx * 8 + 4];
#pragma unroll
      for (int i = 0; i < 8; ++i)
#pragma unroll
        for (int j = 0; j < 8; ++j) acc[i][j] = fmaf(a[i], b[j], acc[i][j]);
    }
  }

  // write xp[c][bn][e], coalesced float4
#pragma unroll
  for (int i = 0; i < 8; ++i) {
    float* op = xp + ((size_t)c * BN + bn0 + ty * 8 + i) * E + tx * 8;
    *(float4*)op       = make_float4(acc[i][0], acc[i][1], acc[i][2], acc[i][3]);
    *(float4*)(op + 4) = make_float4(acc[i][4], acc[i][5], acc[i][6], acc[i][7]);
  }
}

// ---------------------------------------------------------------------------
// K2: for each (c, bn): idx[c][bn] = argmin_m ( e_sq[c][m] - 2 * dots[c][bn][m] )
// grid (4 bn-tiles fast, 256 c slow), 256 threads.
// A (xp tile, 64 rows x 128 k) staged transposed once; codebook streamed in
// 64-m x 64-k half tiles with e_sq accumulated during staging.
// Thread tile 4x4. First-index argmin semantics preserved.
// ---------------------------------------------------------------------------
__global__ __launch_bounds__(256) void k2_argmin(const float* __restrict__ xp,
                                                 const float* __restrict__ cb,
                                                 int* __restrict__ idxo) {
  const int c   = blockIdx.y;
  const int bn0 = blockIdx.x * 64;
  const int tid = threadIdx.x;
  const int ty  = tid >> 4;   // 0..15 -> rows ty*4..+3
  const int tx  = tid & 15;   // 0..15 -> cols tx*4..+3

  __shared__ __align__(16) float As[128][64];   // [k][row]
  __shared__ __align__(16) float Bs[64][64];    // [k_local][m]
  __shared__ float esqp[64][4];

  // stage As: xp[c][bn0+row][*] transposed
  {
    const int row = tid >> 2;           // 0..63
    const int eof = (tid & 3) * 32;
    const float* p = xp + ((size_t)c * BN + bn0 + row) * E + eof;
#pragma unroll
    for (int q = 0; q < 8; ++q) {
      float4 v = *(const float4*)(p + q * 4);
      As[eof + q * 4 + 0][row] = v.x;
      As[eof + q * 4 + 1][row] = v.y;
      As[eof + q * 4 + 2][row] = v.z;
      As[eof + q * 4 + 3][row] = v.w;
    }
  }

  float bestv[4];
  int   besti[4];
#pragma unroll
  for (int i = 0; i < 4; ++i) { bestv[i] = 3.4e38f; besti[i] = 0; }

  const int sm   = tid >> 2;        // 0..63: m row staged by this thread
  const int sq   = tid & 3;
  const int seof = sq * 16;         // e offset within half

  for (int mt = 0; mt < M / 64; ++mt) {
    float acc[4][4];
#pragma unroll
    for (int i = 0; i < 4; ++i)
#pragma unroll
      for (int j = 0; j < 4; ++j) acc[i][j] = 0.0f;
    float esqa = 0.0f;

    const float* cbp = cb + ((size_t)c * M + mt * 64 + sm) * E + seof;

    // ---- half 0: e = 0..63 ----
    __syncthreads();   // prior tile's reads of Bs done
#pragma unroll
    for (int q = 0; q < 4; ++q) {
      float4 v = *(const float4*)(cbp + q * 4);
      esqa = fmaf(v.x, v.x, esqa); esqa = fmaf(v.y, v.y, esqa);
      esqa = fmaf(v.z, v.z, esqa); esqa = fmaf(v.w, v.w, esqa);
      Bs[seof + q * 4 + 0][sm] = v.x;
      Bs[seof + q * 4 + 1][sm] = v.y;
      Bs[seof + q * 4 + 2][sm] = v.z;
      Bs[seof + q * 4 + 3][sm] = v.w;
    }
    __syncthreads();
#pragma unroll
    for (int k = 0; k < 64; ++k) {
      float a[4], b[4];
      *(float4*)a = *(const float4*)&As[k][ty * 4];
      *(float4*)b = *(const float4*)&Bs[k][tx * 4];
#pragma unroll
      for (int i = 0; i < 4; ++i)
#pragma unroll
        for (int j = 0; j < 4; ++j) acc[i][j] = fmaf(a[i], b[j], acc[i][j]);
    }
    __syncthreads();
    // ---- half 1: e = 64..127 ----
#pragma unroll
    for (int q = 0; q < 4; ++q) {
      float4 v = *(const float4*)(cbp + 64 + q * 4);
      esqa = fmaf(v.x, v.x, esqa); esqa = fmaf(v.y, v.y, esqa);
      esqa = fmaf(v.z, v.z, esqa); esqa = fmaf(v.w, v.w, esqa);
      Bs[seof + q * 4 + 0][sm] = v.x;
      Bs[seof + q * 4 + 1][sm] = v.y;
      Bs[seof + q * 4 + 2][sm] = v.z;
      Bs[seof + q * 4 + 3][sm] = v.w;
    }
    esqp[sm][sq] = esqa;
    __syncthreads();
#pragma unroll
    for (int k = 0; k < 64; ++k) {
      float a[4], b[4];
      *(float4*)a = *(const float4*)&As[64 + k][ty * 4];
      *(float4*)b = *(const float4*)&Bs[k][tx * 4];
#pragma unroll
      for (int i = 0; i < 4; ++i)
#pragma unroll
        for (int j = 0; j < 4; ++j) acc[i][j] = fmaf(a[i], b[j], acc[i][j]);
    }
    // ---- epilogue: merge argmin (m ascending within thread -> strict <) ----
#pragma unroll
    for (int j = 0; j < 4; ++j) {
      const int col = tx * 4 + j;
      const float es = esqp[col][0] + esqp[col][1] + esqp[col][2] + esqp[col][3];
      const int mg = mt * 64 + col;
#pragma unroll
      for (int i = 0; i < 4; ++i) {
        float s = fmaf(-2.0f, acc[i][j], es);
        if (s < bestv[i]) { bestv[i] = s; besti[i] = mg; }
      }
    }
  }

  // cross-thread reduction per row (alias scratch over As; As is dead)
  __syncthreads();
  float* redv = &As[0][0];          // 64*16 floats
  int*   redi = (int*)&As[32][0];   // 64*16 ints (8 KB offset, no overlap)
#pragma unroll
  for (int i = 0; i < 4; ++i) {
    redv[(ty * 4 + i) * 16 + tx] = bestv[i];
    redi[(ty * 4 + i) * 16 + tx] = besti[i];
  }
  __syncthreads();
  if (tid < 64) {
    float bv = 3.4e38f; int bi = 0x7fffffff;
    for (int x = 0; x < 16; ++x) {
      float v = redv[tid * 16 + x];
      int   id = redi[tid * 16 + x];
      if (v < bv || (v == bv && id < bi)) { bv = v; bi = id; }
    }
    idxo[c * BN + bn0 + tid] = bi;
  }
}

// ---------------------------------------------------------------------------
// K3: out[bn][v] = mean_c values[c][idx[c][bn]][v]
// one block per bn; thread t handles c = t; tree reduce.
// ---------------------------------------------------------------------------
__global__ __launch_bounds__(256) void k3_gather(const int* __restrict__ idxw,
                                                 const float* __restrict__ vals,
                                                 float* __restrict__ out) {
  const int bn = blockIdx.x;
  const int t  = threadIdx.x;   // = c
  __shared__ float red[256][V];
  const int id = idxw[t * BN + bn];
  const float* vp = vals + ((size_t)t * M + id) * V;
#pragma unroll
  for (int j = 0; j < V; ++j) red[t][j] = vp[j];
  __syncthreads();
  for (int s = 128; s > 0; s >>= 1) {
    if (t < s) {
#pragma unroll
      for (int j = 0; j < V; ++j) red[t][j] += red[t + s][j];
    }
    __syncthreads();
  }
  if (t < V) out[bn * V + t] = red[0][t] * (1.0f / 256.0f);
}

// ---------------------------------------------------------------------------
extern "C" void kernel_launch(void* const* d_in, const int* in_sizes, int n_in,
                              void* d_out, int out_size, void* d_ws, size_t ws_size,
                              hipStream_t stream) {
  const float* emb  = (const float*)d_in[0];  // (4,64,2048)
  const float* proj = (const float*)d_in[1];  // (256,2048,128)
  const float* cb   = (const float*)d_in[2];  // (256,4096,128)
  const float* vals = (const float*)d_in[3];  // (256,4096,10)
  float* out = (float*)d_out;                 // (4,64,10)

  float* xp   = (float*)d_ws;                               // 33,554,432 B
  int*   idxw = (int*)((char*)d_ws + (size_t)C * BN * E * 4); // +256 KB

  k1_xp    <<<dim3(2, C), 256, 0, stream>>>(emb, proj, xp);
  k2_argmin<<<dim3(4, C), 256, 0, stream>>>(xp, cb, idxw);
  k3_gather<<<BN, 256, 0, stream>>>(idxw, vals, out);
}